// Round 1
// baseline (503.333 us; speedup 1.0000x reference)
//
#include <hip/hip_runtime.h>

// L1 loss: sum(|out - target|) / N_VEH over fp32 [8388608, 8].
// Memory-bound: 512 MiB read -> ~85us floor at 6.3 TB/s achievable HBM BW.
// Two-kernel deterministic reduction (no atomics, no reliance on d_out init).

#define NBLOCKS 2048
#define NTHREADS 256

__global__ __launch_bounds__(NTHREADS) void l1_partial_kernel(
    const float4* __restrict__ a, const float4* __restrict__ b,
    float* __restrict__ partial, int n4) {
    int tid = blockIdx.x * NTHREADS + threadIdx.x;
    int stride = gridDim.x * NTHREADS;
    float s = 0.0f;
    for (int i = tid; i < n4; i += stride) {
        float4 x = a[i];
        float4 y = b[i];
        s += fabsf(x.x - y.x);
        s += fabsf(x.y - y.y);
        s += fabsf(x.z - y.z);
        s += fabsf(x.w - y.w);
    }
    // wave-64 shuffle reduction
    #pragma unroll
    for (int off = 32; off > 0; off >>= 1)
        s += __shfl_down(s, off, 64);
    __shared__ float smem[NTHREADS / 64];
    int lane = threadIdx.x & 63;
    int wave = threadIdx.x >> 6;
    if (lane == 0) smem[wave] = s;
    __syncthreads();
    if (threadIdx.x == 0) {
        float t = 0.0f;
        #pragma unroll
        for (int w = 0; w < NTHREADS / 64; ++w) t += smem[w];
        partial[blockIdx.x] = t;
    }
}

__global__ __launch_bounds__(NTHREADS) void l1_final_kernel(
    const float* __restrict__ partial, float* __restrict__ out,
    int nblocks, float inv_n) {
    float s = 0.0f;
    for (int i = threadIdx.x; i < nblocks; i += NTHREADS)
        s += partial[i];
    #pragma unroll
    for (int off = 32; off > 0; off >>= 1)
        s += __shfl_down(s, off, 64);
    __shared__ double smem[NTHREADS / 64];
    int lane = threadIdx.x & 63;
    int wave = threadIdx.x >> 6;
    if (lane == 0) smem[wave] = (double)s;
    __syncthreads();
    if (threadIdx.x == 0) {
        double t = 0.0;
        #pragma unroll
        for (int w = 0; w < NTHREADS / 64; ++w) t += smem[w];
        out[0] = (float)(t * (double)inv_n);
    }
}

extern "C" void kernel_launch(void* const* d_in, const int* in_sizes, int n_in,
                              void* d_out, int out_size, void* d_ws, size_t ws_size,
                              hipStream_t stream) {
    const float* a = (const float*)d_in[0];   // out
    const float* b = (const float*)d_in[1];   // target
    float* out = (float*)d_out;
    float* partial = (float*)d_ws;            // NBLOCKS floats of scratch

    int n = in_sizes[0];          // 67,108,864 (divisible by 4)
    int n4 = n >> 2;
    int n_veh = n >> 3;           // 8 features per vehicle
    float inv_n = 1.0f / (float)n_veh;

    l1_partial_kernel<<<NBLOCKS, NTHREADS, 0, stream>>>(
        (const float4*)a, (const float4*)b, partial, n4);
    l1_final_kernel<<<1, NTHREADS, 0, stream>>>(partial, out, NBLOCKS, inv_n);
}